// Round 1
// baseline (984.002 us; speedup 1.0000x reference)
//
#include <hip/hip_runtime.h>

typedef __attribute__((ext_vector_type(4))) float f4;

#define EPS 1e-5f

// ======================= prep: transposes =======================
// tw[k][j]  = text_w[j][k]   (768 x 256)
// bwT[k][j] = bio_w[j][k]    (32 x 256)
__global__ __launch_bounds__(256) void k_prep_t(const float* __restrict__ text_w,
                                                const float* __restrict__ bio_w,
                                                float* __restrict__ tw,
                                                float* __restrict__ bwT) {
    int j = threadIdx.x;
    int k = blockIdx.x;
    if (k < 768) {
        tw[k * 256 + j] = text_w[j * 768 + k];
    } else {
        int kb = k - 768;
        bwT[kb * 256 + j] = bio_w[j * 32 + kb];
    }
}

// ======================= prep: A = out_w @ Wv, cvec = out_w @ bv + out_b =======================
__global__ __launch_bounds__(256) void k_prep_A(const float* __restrict__ out_w,
                                                const float* __restrict__ in_proj_w,
                                                const float* __restrict__ in_proj_b,
                                                const float* __restrict__ out_b,
                                                float* __restrict__ A,
                                                float* __restrict__ cvec) {
    __shared__ float srow[256];
    __shared__ float red[256];
    int i = blockIdx.x, j = threadIdx.x;
    srow[j] = out_w[i * 256 + j];
    __syncthreads();
    float acc = 0.f;
#pragma unroll 8
    for (int k = 0; k < 256; k++)
        acc = fmaf(srow[k], in_proj_w[(512 + k) * 256 + j], acc);
    A[i * 256 + j] = acc;
    red[j] = srow[j] * in_proj_b[512 + j];
    __syncthreads();
    for (int s = 128; s > 0; s >>= 1) {
        if (j < s) red[j] += red[j + s];
        __syncthreads();
    }
    if (j == 0) cvec[i] = red[0] + out_b[i];
}

// ======================= prep: PQt (stacked, transposed, LN-gain folded), dvec =======================
// PQt[j][i]     = (W1@A)[i][j] * ln_text_g[j]          j in [0,256)
// PQt[256+j][i] = (W2@A)[i][j] * ln_bio_g[j]
// dvec[i] = sum_j (W1@A)[i][j]*ln_text_b[j] + (W2@A)[i][j]*ln_bio_b[j]
//         + sum_k (W1+W2)[i][k]*cvec[k] + cls1_b[i]
__global__ __launch_bounds__(256) void k_prep_PQ(const float* __restrict__ cls1_w,
                                                 const float* __restrict__ cls1_b,
                                                 const float* __restrict__ A,
                                                 const float* __restrict__ cvec,
                                                 const float* __restrict__ ln_text_g,
                                                 const float* __restrict__ ln_text_b,
                                                 const float* __restrict__ ln_bio_g,
                                                 const float* __restrict__ ln_bio_b,
                                                 float* __restrict__ PQt,
                                                 float* __restrict__ dvec) {
    __shared__ float w1[256], w2[256], red[256];
    int i = blockIdx.x, j = threadIdx.x;
    w1[j] = cls1_w[i * 512 + j];
    w2[j] = cls1_w[i * 512 + 256 + j];
    __syncthreads();
    float rp = 0.f, rq = 0.f;
#pragma unroll 4
    for (int k = 0; k < 256; k++) {
        float a = A[k * 256 + j];
        rp = fmaf(w1[k], a, rp);
        rq = fmaf(w2[k], a, rq);
    }
    PQt[j * 256 + i]         = rp * ln_text_g[j];
    PQt[(256 + j) * 256 + i] = rq * ln_bio_g[j];
    red[j] = rp * ln_text_b[j] + rq * ln_bio_b[j] + (w1[j] + w2[j]) * cvec[j];
    __syncthreads();
    for (int s = 128; s > 0; s >>= 1) {
        if (j < s) red[j] += red[j + s];
        __syncthreads();
    }
    if (j == 0) dvec[i] = red[0] + cls1_b[i];
}

// ======================= main fused kernel =======================
// Block: 256 threads = 4 waves; wave rg owns 4 rows (rg*4..rg*4+3).
// Lane owns 4 columns (lane*4..lane*4+3). 16 rows per block, grid 4096.
__global__ __launch_bounds__(256) void k_main(
    const float* __restrict__ bio, const float* __restrict__ text,
    const float* __restrict__ bio_b, const float* __restrict__ text_b,
    const float* __restrict__ cls_ln_g, const float* __restrict__ cls_ln_b,
    const float* __restrict__ cls2_w, const float* __restrict__ cls2_b,
    const float* __restrict__ tw, const float* __restrict__ bwT,
    const float* __restrict__ PQt, const float* __restrict__ dvec,
    float* __restrict__ out)
{
    __shared__ float s_text[16 * 192];   // 12 KB  k-chunk of text tile
    __shared__ float s_n[16 * 512];      // 32 KB  [n_t | n_b] per row
    __shared__ float s_bio[16 * 32];     //  2 KB

    const int tid  = threadIdx.x;
    const int lane = tid & 63;
    const int rg   = tid >> 6;          // wave id = row group
    const int c0   = lane * 4;          // this lane's 4 columns
    const int R0   = blockIdx.x * 16;

    float acc[4][4];

    // ---------------- stage A: x_b = bio @ bio_w.T + bio_b ; n_b ----------------
    if (tid < 128) {
        int row = tid >> 3, c4 = tid & 7;
        *(f4*)&s_bio[row * 32 + c4 * 4] =
            *(const f4*)&bio[(size_t)(R0 + row) * 32 + c4 * 4];
    }
    __syncthreads();

#pragma unroll
    for (int r = 0; r < 4; r++)
#pragma unroll
        for (int c = 0; c < 4; c++) acc[r][c] = 0.f;

#pragma unroll
    for (int k = 0; k < 32; k += 4) {
        f4 w4[4], x4[4];
#pragma unroll
        for (int i = 0; i < 4; i++) w4[i] = *(const f4*)&bwT[(k + i) * 256 + c0];
#pragma unroll
        for (int r = 0; r < 4; r++) x4[r] = *(const f4*)&s_bio[(rg * 4 + r) * 32 + k];
#pragma unroll
        for (int r = 0; r < 4; r++)
#pragma unroll
            for (int i = 0; i < 4; i++)
#pragma unroll
                for (int c = 0; c < 4; c++)
                    acc[r][c] = fmaf(x4[r][i], w4[i][c], acc[r][c]);
    }
    {
        f4 bb = *(const f4*)&bio_b[c0];
        float s1[4], s2[4];
#pragma unroll
        for (int r = 0; r < 4; r++) {
            s1[r] = 0.f; s2[r] = 0.f;
#pragma unroll
            for (int c = 0; c < 4; c++) {
                float x = acc[r][c] + bb[c];
                acc[r][c] = x;
                s1[r] += x; s2[r] += x * x;
            }
        }
#pragma unroll
        for (int off = 1; off < 64; off <<= 1)
#pragma unroll
            for (int r = 0; r < 4; r++) {
                s1[r] += __shfl_xor(s1[r], off, 64);
                s2[r] += __shfl_xor(s2[r], off, 64);
            }
#pragma unroll
        for (int r = 0; r < 4; r++) {
            float m   = s1[r] * (1.f / 256.f);
            float var = s2[r] * (1.f / 256.f) - m * m;
            float inv = rsqrtf(var + EPS);
            f4 nv;
#pragma unroll
            for (int c = 0; c < 4; c++) nv[c] = (acc[r][c] - m) * inv;
            *(f4*)&s_n[(rg * 4 + r) * 512 + 256 + c0] = nv;
        }
    }

    // ---------------- stage B: x_t = text @ text_w.T + text_b ; n_t ----------------
#pragma unroll
    for (int r = 0; r < 4; r++)
#pragma unroll
        for (int c = 0; c < 4; c++) acc[r][c] = 0.f;

    for (int kc = 0; kc < 768; kc += 192) {
        __syncthreads();
#pragma unroll
        for (int it = 0; it < 3; it++) {
            int idx = tid + it * 256;       // 0..767 float4 slots
            int row = idx / 48;
            int c4  = idx % 48;
            *(f4*)&s_text[row * 192 + c4 * 4] =
                *(const f4*)&text[(size_t)(R0 + row) * 768 + kc + c4 * 4];
        }
        __syncthreads();
#pragma unroll 2
        for (int k = 0; k < 192; k += 4) {
            f4 w4[4], x4[4];
#pragma unroll
            for (int i = 0; i < 4; i++) w4[i] = *(const f4*)&tw[(kc + k + i) * 256 + c0];
#pragma unroll
            for (int r = 0; r < 4; r++) x4[r] = *(const f4*)&s_text[(rg * 4 + r) * 192 + k];
#pragma unroll
            for (int r = 0; r < 4; r++)
#pragma unroll
                for (int i = 0; i < 4; i++)
#pragma unroll
                    for (int c = 0; c < 4; c++)
                        acc[r][c] = fmaf(x4[r][i], w4[i][c], acc[r][c]);
        }
    }
    {
        f4 tb = *(const f4*)&text_b[c0];
        float s1[4], s2[4];
#pragma unroll
        for (int r = 0; r < 4; r++) {
            s1[r] = 0.f; s2[r] = 0.f;
#pragma unroll
            for (int c = 0; c < 4; c++) {
                float x = acc[r][c] + tb[c];
                acc[r][c] = x;
                s1[r] += x; s2[r] += x * x;
            }
        }
#pragma unroll
        for (int off = 1; off < 64; off <<= 1)
#pragma unroll
            for (int r = 0; r < 4; r++) {
                s1[r] += __shfl_xor(s1[r], off, 64);
                s2[r] += __shfl_xor(s2[r], off, 64);
            }
#pragma unroll
        for (int r = 0; r < 4; r++) {
            float m   = s1[r] * (1.f / 256.f);
            float var = s2[r] * (1.f / 256.f) - m * m;
            float inv = rsqrtf(var + EPS);
            f4 nv;
#pragma unroll
            for (int c = 0; c < 4; c++) nv[c] = (acc[r][c] - m) * inv;
            *(f4*)&s_n[(rg * 4 + r) * 512 + c0] = nv;
        }
    }
    __syncthreads();

    // ---------------- stage D: z = P@n_t + Q@n_b + d ----------------
    float accz[4][4];
    {
        f4 dv = *(const f4*)&dvec[c0];
#pragma unroll
        for (int r = 0; r < 4; r++)
#pragma unroll
            for (int c = 0; c < 4; c++) accz[r][c] = dv[c];
    }
#pragma unroll 2
    for (int k = 0; k < 512; k += 4) {
        f4 w4[4], x4[4];
#pragma unroll
        for (int i = 0; i < 4; i++) w4[i] = *(const f4*)&PQt[(k + i) * 256 + c0];
#pragma unroll
        for (int r = 0; r < 4; r++) x4[r] = *(const f4*)&s_n[(rg * 4 + r) * 512 + k];
#pragma unroll
        for (int r = 0; r < 4; r++)
#pragma unroll
            for (int i = 0; i < 4; i++)
#pragma unroll
                for (int c = 0; c < 4; c++)
                    accz[r][c] = fmaf(x4[r][i], w4[i][c], accz[r][c]);
    }

    // ---------------- epilogue: LN(z), relu, cls2 ----------------
    {
        float s1[4], s2[4];
#pragma unroll
        for (int r = 0; r < 4; r++) {
            s1[r] = 0.f; s2[r] = 0.f;
#pragma unroll
            for (int c = 0; c < 4; c++) {
                float x = accz[r][c];
                s1[r] += x; s2[r] += x * x;
            }
        }
#pragma unroll
        for (int off = 1; off < 64; off <<= 1)
#pragma unroll
            for (int r = 0; r < 4; r++) {
                s1[r] += __shfl_xor(s1[r], off, 64);
                s2[r] += __shfl_xor(s2[r], off, 64);
            }
        f4 g   = *(const f4*)&cls_ln_g[c0];
        f4 be  = *(const f4*)&cls_ln_b[c0];
        f4 cw0 = *(const f4*)&cls2_w[c0];
        f4 cw1 = *(const f4*)&cls2_w[256 + c0];
        float po[4][2];
#pragma unroll
        for (int r = 0; r < 4; r++) {
            float m   = s1[r] * (1.f / 256.f);
            float var = s2[r] * (1.f / 256.f) - m * m;
            float inv = rsqrtf(var + EPS);
            po[r][0] = 0.f; po[r][1] = 0.f;
#pragma unroll
            for (int c = 0; c < 4; c++) {
                float h = (accz[r][c] - m) * inv * g[c] + be[c];
                h = fmaxf(h, 0.f);
                po[r][0] = fmaf(h, cw0[c], po[r][0]);
                po[r][1] = fmaf(h, cw1[c], po[r][1]);
            }
        }
#pragma unroll
        for (int off = 1; off < 64; off <<= 1)
#pragma unroll
            for (int r = 0; r < 4; r++) {
                po[r][0] += __shfl_xor(po[r][0], off, 64);
                po[r][1] += __shfl_xor(po[r][1], off, 64);
            }
        if (lane == 0) {
            float b0 = cls2_b[0], b1 = cls2_b[1];
#pragma unroll
            for (int r = 0; r < 4; r++) {
                size_t ro = (size_t)(R0 + rg * 4 + r) * 2;
                out[ro]     = po[r][0] + b0;
                out[ro + 1] = po[r][1] + b1;
            }
        }
    }
}

// ======================= launch =======================
extern "C" void kernel_launch(void* const* d_in, const int* in_sizes, int n_in,
                              void* d_out, int out_size, void* d_ws, size_t ws_size,
                              hipStream_t stream) {
    const float* bio       = (const float*)d_in[0];
    const float* text      = (const float*)d_in[1];
    const float* bio_w     = (const float*)d_in[2];
    const float* bio_b     = (const float*)d_in[3];
    const float* text_w    = (const float*)d_in[4];
    const float* text_b    = (const float*)d_in[5];
    const float* ln_bio_g  = (const float*)d_in[6];
    const float* ln_bio_b  = (const float*)d_in[7];
    const float* ln_text_g = (const float*)d_in[8];
    const float* ln_text_b = (const float*)d_in[9];
    const float* in_proj_w = (const float*)d_in[10];
    const float* in_proj_b = (const float*)d_in[11];
    const float* out_w     = (const float*)d_in[12];
    const float* out_b     = (const float*)d_in[13];
    const float* cls1_w    = (const float*)d_in[14];
    const float* cls1_b    = (const float*)d_in[15];
    const float* cls_ln_g  = (const float*)d_in[16];
    const float* cls_ln_b  = (const float*)d_in[17];
    const float* cls2_w    = (const float*)d_in[18];
    const float* cls2_b    = (const float*)d_in[19];
    float* out = (float*)d_out;

    float* ws   = (float*)d_ws;
    float* tw   = ws;               // 768*256 = 196608
    float* bwT  = ws + 196608;      // 32*256  = 8192
    float* A    = ws + 204800;      // 256*256 = 65536
    float* cvec = ws + 270336;      // 256
    float* PQt  = ws + 270592;      // 512*256 = 131072
    float* dvec = ws + 401664;      // 256     (total 401920 floats = 1.6 MB)

    k_prep_t<<<800, 256, 0, stream>>>(text_w, bio_w, tw, bwT);
    k_prep_A<<<256, 256, 0, stream>>>(out_w, in_proj_w, in_proj_b, out_b, A, cvec);
    k_prep_PQ<<<256, 256, 0, stream>>>(cls1_w, cls1_b, A, cvec,
                                       ln_text_g, ln_text_b, ln_bio_g, ln_bio_b,
                                       PQt, dvec);

    int nrows = in_sizes[0] / 32;   // 65536
    k_main<<<nrows / 16, 256, 0, stream>>>(bio, text, bio_b, text_b,
                                           cls_ln_g, cls_ln_b, cls2_w, cls2_b,
                                           tw, bwT, PQt, dvec, out);
}

// Round 2
// 407.321 us; speedup vs baseline: 2.4158x; 2.4158x over previous
//
#include <hip/hip_runtime.h>

typedef __attribute__((ext_vector_type(4))) float f4;
typedef __attribute__((ext_vector_type(8))) short s8;   // 8 bf16 in 4 VGPRs (MFMA A/B frag)

#define EPS 1e-5f

__device__ __forceinline__ unsigned short f2bf(float f) {
    union { float f; unsigned u; } v; v.f = f;
    unsigned u = v.u;
    return (unsigned short)((u + 0x7fffu + ((u >> 16) & 1u)) >> 16);   // RNE
}
__device__ __forceinline__ unsigned pack2(float a, float b) {
    return (unsigned)f2bf(a) | ((unsigned)f2bf(b) << 16);
}

// =================== prep: weights -> fragment-linear bf16 ===================
// FL layout: FL[((ksg*16 + ct)*64 + lane)*8 + j] = W[ct*16 + (lane&15)][ksg*32 + (lane>>4)*8 + j]
// so a wave's B-frag load for (ksg, ct) is one coalesced 16B/lane read.
__global__ __launch_bounds__(256) void k_prep_fl(const float* __restrict__ text_w,
                                                 const float* __restrict__ bio_w,
                                                 unsigned short* __restrict__ twFL,
                                                 unsigned short* __restrict__ bwFL) {
    int b = blockIdx.x, t = threadIdx.x;
    if (b < 96) {                       // text_w [256][768] -> 24 ksteps x 16 ct
        int idx = b * 256 + t;          // 0..24575
        int ksg = idx >> 10;
        int rem = idx & 1023;
        int ct = rem >> 6, lane = rem & 63;
        int n  = ct * 16 + (lane & 15);
        int k0 = ksg * 32 + ((lane >> 4) << 3);
        const float* src = &text_w[n * 768 + k0];
        f4 a = *(const f4*)src, c = *(const f4*)(src + 4);
        unsigned* dst = (unsigned*)&twFL[idx * 8];
        dst[0] = pack2(a[0], a[1]); dst[1] = pack2(a[2], a[3]);
        dst[2] = pack2(c[0], c[1]); dst[3] = pack2(c[2], c[3]);
    } else {                            // bio_w [256][32] -> 1 kstep x 16 ct
        int idx = (b - 96) * 256 + t;   // 0..1023
        int ct = idx >> 6, lane = idx & 63;
        int n  = ct * 16 + (lane & 15);
        int k0 = (lane >> 4) << 3;
        const float* src = &bio_w[n * 32 + k0];
        f4 a = *(const f4*)src, c = *(const f4*)(src + 4);
        unsigned* dst = (unsigned*)&bwFL[idx * 8];
        dst[0] = pack2(a[0], a[1]); dst[1] = pack2(a[2], a[3]);
        dst[2] = pack2(c[0], c[1]); dst[3] = pack2(c[2], c[3]);
    }
}

// =================== prep: A = out_w @ Wv, cvec = out_w @ bv + out_b ===================
__global__ __launch_bounds__(256) void k_prep_A(const float* __restrict__ out_w,
                                                const float* __restrict__ in_proj_w,
                                                const float* __restrict__ in_proj_b,
                                                const float* __restrict__ out_b,
                                                float* __restrict__ A,
                                                float* __restrict__ cvec) {
    __shared__ float srow[256];
    __shared__ float red[256];
    int i = blockIdx.x, j = threadIdx.x;
    srow[j] = out_w[i * 256 + j];
    __syncthreads();
    float acc = 0.f;
#pragma unroll 8
    for (int k = 0; k < 256; k++)
        acc = fmaf(srow[k], in_proj_w[(512 + k) * 256 + j], acc);
    A[i * 256 + j] = acc;
    red[j] = srow[j] * in_proj_b[512 + j];
    __syncthreads();
    for (int s = 128; s > 0; s >>= 1) {
        if (j < s) red[j] += red[j + s];
        __syncthreads();
    }
    if (j == 0) cvec[i] = red[0] + out_b[i];
}

// =================== prep: PQ weights (frag-linear bf16, LN-gain folded) + dvec ===================
// z = Wpq @ [n_t ; n_b] + dvec, Wpq[n=i][k]: k<256 -> (W1@A)[i][k]*g_t[k]; k>=256 -> (W2@A)[i][k-256]*g_b[..]
__global__ __launch_bounds__(256) void k_prep_PQ(const float* __restrict__ cls1_w,
                                                 const float* __restrict__ cls1_b,
                                                 const float* __restrict__ A,
                                                 const float* __restrict__ cvec,
                                                 const float* __restrict__ ln_text_g,
                                                 const float* __restrict__ ln_text_b,
                                                 const float* __restrict__ ln_bio_g,
                                                 const float* __restrict__ ln_bio_b,
                                                 unsigned short* __restrict__ pqFL,
                                                 float* __restrict__ dvec) {
    __shared__ float w1[256], w2[256], red[256];
    int i = blockIdx.x, j = threadIdx.x;
    w1[j] = cls1_w[i * 512 + j];
    w2[j] = cls1_w[i * 512 + 256 + j];
    __syncthreads();
    float rp = 0.f, rq = 0.f;
#pragma unroll 4
    for (int k = 0; k < 256; k++) {
        float a = A[k * 256 + j];
        rp = fmaf(w1[k], a, rp);
        rq = fmaf(w2[k], a, rq);
    }
    // frag-linear positions for element (n=i, k=j) and (n=i, k=256+j)
    int ct   = i >> 4;
    int lane = (i & 15) | (((j >> 3) & 3) << 4);
    int jj   = j & 7;
    int ks1  = j >> 5;
    pqFL[(((ks1     ) * 16 + ct) * 64 + lane) * 8 + jj] = f2bf(rp * ln_text_g[j]);
    pqFL[(((ks1 + 8 ) * 16 + ct) * 64 + lane) * 8 + jj] = f2bf(rq * ln_bio_g[j]);
    red[j] = rp * ln_text_b[j] + rq * ln_bio_b[j] + (w1[j] + w2[j]) * cvec[j];
    __syncthreads();
    for (int s = 128; s > 0; s >>= 1) {
        if (j < s) red[j] += red[j + s];
        __syncthreads();
    }
    if (j == 0) dvec[i] = red[0] + cls1_b[i];
}

// =================== main fused MFMA kernel ===================
// block = 32 rows, 4 waves; wave w owns col-slice [w*64, w*64+64), 2 row-tiles of 16.
// mfma_f32_16x16x32_bf16 frags (verified layouts):
//   A: lane holds A[m=lane&15][k=(lane>>4)*8+j]   B: lane holds B[k=(lane>>4)*8+j][n=lane&15]
//   C/D: lane reg r -> row=(lane>>4)*4+r, col=lane&15
__global__ __launch_bounds__(256, 3) void k_main(
    const float* __restrict__ bio, const float* __restrict__ text,
    const float* __restrict__ bio_b, const float* __restrict__ text_b,
    const float* __restrict__ cls_ln_g, const float* __restrict__ cls_ln_b,
    const float* __restrict__ cls2_w, const float* __restrict__ cls2_b,
    const unsigned short* __restrict__ twFL, const unsigned short* __restrict__ bwFL,
    const unsigned short* __restrict__ pqFL, const float* __restrict__ dvec,
    float* __restrict__ out)
{
    __shared__ __align__(16) unsigned short s_n[32][520];  // [row][k] n_t: 0..255, n_b: 256..511 (+8 pad)
    __shared__ __align__(16) unsigned short s_x[32][200];  // text chunk bf16, BK=192 (+8 pad)
    __shared__ __align__(16) unsigned short s_b[32][40];   // bio bf16 (+8 pad)
    __shared__ float s_red[4][32][2];                      // per-wave row partials

    const int tid  = threadIdx.x;
    const int w    = tid >> 6;
    const int lane = tid & 63;
    const int q    = lane >> 4;
    const int lr   = lane & 15;
    const int R0   = blockIdx.x * 32;

    f4 acc[2][4];
    float s1[2][4], s2[2][4];
    float m_[2][4], iv_[2][4];

    // ---------------- stage bio -> LDS bf16 ----------------
    {
        int row = tid >> 3, c4 = tid & 7;
        f4 v = *(const f4*)&bio[(size_t)(R0 + row) * 32 + c4 * 4];
        uint2 p; p.x = pack2(v[0], v[1]); p.y = pack2(v[2], v[3]);
        *(uint2*)&s_b[row][c4 * 4] = p;
    }
    __syncthreads();

    // ---------------- stage A: x_b = bio @ bio_w.T + bio_b (K=32, one mfma) ----------------
#pragma unroll
    for (int rt = 0; rt < 2; rt++)
#pragma unroll
        for (int c = 0; c < 4; c++) acc[rt][c] = (f4){0.f, 0.f, 0.f, 0.f};
    {
        s8 bfr[4];
#pragma unroll
        for (int c = 0; c < 4; c++)
            bfr[c] = *(const s8*)&bwFL[((w * 4 + c) * 64 + lane) * 8];
#pragma unroll
        for (int rt = 0; rt < 2; rt++) {
            s8 afr = *(const s8*)&s_b[rt * 16 + lr][q * 8];
#pragma unroll
            for (int c = 0; c < 4; c++)
                acc[rt][c] = __builtin_amdgcn_mfma_f32_16x16x32_bf16(afr, bfr[c], acc[rt][c], 0, 0, 0);
        }
    }
    // bias + LN stats
#pragma unroll
    for (int rt = 0; rt < 2; rt++)
#pragma unroll
        for (int r = 0; r < 4; r++) { s1[rt][r] = 0.f; s2[rt][r] = 0.f; }
#pragma unroll
    for (int rt = 0; rt < 2; rt++)
#pragma unroll
        for (int c = 0; c < 4; c++) {
            float bb = bio_b[w * 64 + c * 16 + lr];
#pragma unroll
            for (int r = 0; r < 4; r++) {
                float x = acc[rt][c][r] + bb;
                acc[rt][c][r] = x;
                s1[rt][r] += x; s2[rt][r] += x * x;
            }
        }
#pragma unroll
    for (int off = 1; off < 16; off <<= 1)
#pragma unroll
        for (int rt = 0; rt < 2; rt++)
#pragma unroll
            for (int r = 0; r < 4; r++) {
                s1[rt][r] += __shfl_xor(s1[rt][r], off, 64);
                s2[rt][r] += __shfl_xor(s2[rt][r], off, 64);
            }
    if (lr == 0)
#pragma unroll
        for (int rt = 0; rt < 2; rt++)
#pragma unroll
            for (int r = 0; r < 4; r++) {
                int row = rt * 16 + q * 4 + r;
                s_red[w][row][0] = s1[rt][r];
                s_red[w][row][1] = s2[rt][r];
            }
    __syncthreads();
#pragma unroll
    for (int rt = 0; rt < 2; rt++)
#pragma unroll
        for (int r = 0; r < 4; r++) {
            int row = rt * 16 + q * 4 + r;
            float t1 = s_red[0][row][0] + s_red[1][row][0] + s_red[2][row][0] + s_red[3][row][0];
            float t2 = s_red[0][row][1] + s_red[1][row][1] + s_red[2][row][1] + s_red[3][row][1];
            float mm = t1 * (1.f / 256.f);
            float vv = t2 * (1.f / 256.f) - mm * mm;
            m_[rt][r]  = mm;
            iv_[rt][r] = rsqrtf(vv + EPS);
        }
#pragma unroll
    for (int rt = 0; rt < 2; rt++)
#pragma unroll
        for (int c = 0; c < 4; c++) {
            int col = w * 64 + c * 16 + lr;
#pragma unroll
            for (int r = 0; r < 4; r++)
                s_n[rt * 16 + q * 4 + r][256 + col] = f2bf((acc[rt][c][r] - m_[rt][r]) * iv_[rt][r]);
        }

    // ---------------- stage B: x_t = text @ text_w.T + text_b (K=768) ----------------
#pragma unroll
    for (int rt = 0; rt < 2; rt++)
#pragma unroll
        for (int c = 0; c < 4; c++) acc[rt][c] = (f4){0.f, 0.f, 0.f, 0.f};

    for (int kc = 0; kc < 768; kc += 192) {
        __syncthreads();
#pragma unroll
        for (int i = 0; i < 6; i++) {
            int idx = tid + i * 256;          // 1536 f4-groups: 32 rows x 48
            int row = idx / 48;
            int c4  = idx % 48;
            f4 v = *(const f4*)&text[(size_t)(R0 + row) * 768 + kc + c4 * 4];
            uint2 p; p.x = pack2(v[0], v[1]); p.y = pack2(v[2], v[3]);
            *(uint2*)&s_x[row][c4 * 4] = p;
        }
        __syncthreads();
        int ksg0 = kc >> 5;
#pragma unroll
        for (int ks = 0; ks < 6; ks++) {
            s8 bfr[4];
#pragma unroll
            for (int c = 0; c < 4; c++)
                bfr[c] = *(const s8*)&twFL[(((ksg0 + ks) * 16 + w * 4 + c) * 64 + lane) * 8];
#pragma unroll
            for (int rt = 0; rt < 2; rt++) {
                s8 afr = *(const s8*)&s_x[rt * 16 + lr][ks * 32 + q * 8];
#pragma unroll
                for (int c = 0; c < 4; c++)
                    acc[rt][c] = __builtin_amdgcn_mfma_f32_16x16x32_bf16(afr, bfr[c], acc[rt][c], 0, 0, 0);
            }
        }
    }
    // bias + LN stats
#pragma unroll
    for (int rt = 0; rt < 2; rt++)
#pragma unroll
        for (int r = 0; r < 4; r++) { s1[rt][r] = 0.f; s2[rt][r] = 0.f; }
#pragma unroll
    for (int rt = 0; rt < 2; rt++)
#pragma unroll
        for (int c = 0; c < 4; c++) {
            float bb = text_b[w * 64 + c * 16 + lr];
#pragma unroll
            for (int r = 0; r < 4; r++) {
                float x = acc[rt][c][r] + bb;
                acc[rt][c][r] = x;
                s1[rt][r] += x; s2[rt][r] += x * x;
            }
        }
#pragma unroll
    for (int off = 1; off < 16; off <<= 1)
#pragma unroll
        for (int rt = 0; rt < 2; rt++)
#pragma unroll
            for (int r = 0; r < 4; r++) {
                s1[rt][r] += __shfl_xor(s1[rt][r], off, 64);
                s2[rt][r] += __shfl_xor(s2[rt][r], off, 64);
            }
    __syncthreads();   // all waves past chunk loop; safe to rewrite s_red
    if (lr == 0)
#pragma unroll
        for (int rt = 0; rt < 2; rt++)
#pragma unroll
            for (int r = 0; r < 4; r++) {
                int row = rt * 16 + q * 4 + r;
                s_red[w][row][0] = s1[rt][r];
                s_red[w][row][1] = s2[rt][r];
            }
    __syncthreads();
#pragma unroll
    for (int rt = 0; rt < 2; rt++)
#pragma unroll
        for (int r = 0; r < 4; r++) {
            int row = rt * 16 + q * 4 + r;
            float t1 = s_red[0][row][0] + s_red[1][row][0] + s_red[2][row][0] + s_red[3][row][0];
            float t2 = s_red[0][row][1] + s_red[1][row][1] + s_red[2][row][1] + s_red[3][row][1];
            float mm = t1 * (1.f / 256.f);
            float vv = t2 * (1.f / 256.f) - mm * mm;
            m_[rt][r]  = mm;
            iv_[rt][r] = rsqrtf(vv + EPS);
        }
#pragma unroll
    for (int rt = 0; rt < 2; rt++)
#pragma unroll
        for (int c = 0; c < 4; c++) {
            int col = w * 64 + c * 16 + lr;
#pragma unroll
            for (int r = 0; r < 4; r++)
                s_n[rt * 16 + q * 4 + r][col] = f2bf((acc[rt][c][r] - m_[rt][r]) * iv_[rt][r]);
        }
    __syncthreads();   // full s_n ([n_t | n_b]) ready for all waves

    // ---------------- stage D: z = Wpq @ [n_t ; n_b] + dvec (K=512) ----------------
#pragma unroll
    for (int rt = 0; rt < 2; rt++)
#pragma unroll
        for (int c = 0; c < 4; c++) {
            float dv = dvec[w * 64 + c * 16 + lr];
            acc[rt][c] = (f4){dv, dv, dv, dv};
        }
#pragma unroll 4
    for (int ks = 0; ks < 16; ks++) {
        s8 bfr[4];
#pragma unroll
        for (int c = 0; c < 4; c++)
            bfr[c] = *(const s8*)&pqFL[((ks * 16 + w * 4 + c) * 64 + lane) * 8];
#pragma unroll
        for (int rt = 0; rt < 2; rt++) {
            s8 afr = *(const s8*)&s_n[rt * 16 + lr][ks * 32 + q * 8];
#pragma unroll
            for (int c = 0; c < 4; c++)
                acc[rt][c] = __builtin_amdgcn_mfma_f32_16x16x32_bf16(afr, bfr[c], acc[rt][c], 0, 0, 0);
        }
    }

    // ---------------- epilogue: LN(z), relu, cls2 ----------------
#pragma unroll
    for (int rt = 0; rt < 2; rt++)
#pragma unroll
        for (int r = 0; r < 4; r++) { s1[rt][r] = 0.f; s2[rt][r] = 0.f; }
#pragma unroll
    for (int rt = 0; rt < 2; rt++)
#pragma unroll
        for (int c = 0; c < 4; c++)
#pragma unroll
            for (int r = 0; r < 4; r++) {
                float x = acc[rt][c][r];
                s1[rt][r] += x; s2[rt][r] += x * x;
            }
#pragma unroll
    for (int off = 1; off < 16; off <<= 1)
#pragma unroll
        for (int rt = 0; rt < 2; rt++)
#pragma unroll
            for (int r = 0; r < 4; r++) {
                s1[rt][r] += __shfl_xor(s1[rt][r], off, 64);
                s2[rt][r] += __shfl_xor(s2[rt][r], off, 64);
            }
    if (lr == 0)
#pragma unroll
        for (int rt = 0; rt < 2; rt++)
#pragma unroll
            for (int r = 0; r < 4; r++) {
                int row = rt * 16 + q * 4 + r;
                s_red[w][row][0] = s1[rt][r];
                s_red[w][row][1] = s2[rt][r];
            }
    __syncthreads();
#pragma unroll
    for (int rt = 0; rt < 2; rt++)
#pragma unroll
        for (int r = 0; r < 4; r++) {
            int row = rt * 16 + q * 4 + r;
            float t1 = s_red[0][row][0] + s_red[1][row][0] + s_red[2][row][0] + s_red[3][row][0];
            float t2 = s_red[0][row][1] + s_red[1][row][1] + s_red[2][row][1] + s_red[3][row][1];
            float mm = t1 * (1.f / 256.f);
            float vv = t2 * (1.f / 256.f) - mm * mm;
            m_[rt][r]  = mm;
            iv_[rt][r] = rsqrtf(vv + EPS);
        }
    float po0[2][4], po1[2][4];
#pragma unroll
    for (int rt = 0; rt < 2; rt++)
#pragma unroll
        for (int r = 0; r < 4; r++) { po0[rt][r] = 0.f; po1[rt][r] = 0.f; }
#pragma unroll
    for (int rt = 0; rt < 2; rt++)
#pragma unroll
        for (int c = 0; c < 4; c++) {
            int col = w * 64 + c * 16 + lr;
            float gg = cls_ln_g[col], bb = cls_ln_b[col];
            float c0 = cls2_w[col],   c1 = cls2_w[256 + col];
#pragma unroll
            for (int r = 0; r < 4; r++) {
                float h = fmaxf((acc[rt][c][r] - m_[rt][r]) * iv_[rt][r] * gg + bb, 0.f);
                po0[rt][r] = fmaf(h, c0, po0[rt][r]);
                po1[rt][r] = fmaf(h, c1, po1[rt][r]);
            }
        }
#pragma unroll
    for (int off = 1; off < 16; off <<= 1)
#pragma unroll
        for (int rt = 0; rt < 2; rt++)
#pragma unroll
            for (int r = 0; r < 4; r++) {
                po0[rt][r] += __shfl_xor(po0[rt][r], off, 64);
                po1[rt][r] += __shfl_xor(po1[rt][r], off, 64);
            }
    __syncthreads();   // stats reads done; safe to rewrite s_red
    if (lr == 0)
#pragma unroll
        for (int rt = 0; rt < 2; rt++)
#pragma unroll
            for (int r = 0; r < 4; r++) {
                int row = rt * 16 + q * 4 + r;
                s_red[w][row][0] = po0[rt][r];
                s_red[w][row][1] = po1[rt][r];
            }
    __syncthreads();
    if (tid < 64) {
        int row = tid >> 1, comp = tid & 1;
        float v = s_red[0][row][comp] + s_red[1][row][comp] +
                  s_red[2][row][comp] + s_red[3][row][comp];
        out[(size_t)(R0 + row) * 2 + comp] = v + cls2_b[comp];
    }
}

// ======================= launch =======================
extern "C" void kernel_launch(void* const* d_in, const int* in_sizes, int n_in,
                              void* d_out, int out_size, void* d_ws, size_t ws_size,
                              hipStream_t stream) {
    const float* bio       = (const float*)d_in[0];
    const float* text      = (const float*)d_in[1];
    const float* bio_w     = (const float*)d_in[2];
    const float* bio_b     = (const float*)d_in[3];
    const float* text_w    = (const float*)d_in[4];
    const float* text_b    = (const float*)d_in[5];
    const float* ln_bio_g  = (const float*)d_in[6];
    const float* ln_bio_b  = (const float*)d_in[7];
    const float* ln_text_g = (const float*)d_in[8];
    const float* ln_text_b = (const float*)d_in[9];
    const float* in_proj_w = (const float*)d_in[10];
    const float* in_proj_b = (const float*)d_in[11];
    const float* out_w     = (const float*)d_in[12];
    const float* out_b     = (const float*)d_in[13];
    const float* cls1_w    = (const float*)d_in[14];
    const float* cls1_b    = (const float*)d_in[15];
    const float* cls_ln_g  = (const float*)d_in[16];
    const float* cls_ln_b  = (const float*)d_in[17];
    const float* cls2_w    = (const float*)d_in[18];
    const float* cls2_b    = (const float*)d_in[19];
    float* out = (float*)d_out;

    float* ws   = (float*)d_ws;
    float* A    = ws;                 // 65536 fp32
    float* cvec = ws + 65536;         // 256
    float* dvec = ws + 65792;         // 256
    unsigned short* us   = (unsigned short*)(ws + 66048);
    unsigned short* twFL = us;            // 196608 bf16
    unsigned short* bwFL = us + 196608;   // 8192
    unsigned short* pqFL = us + 204800;   // 131072

    k_prep_fl<<<100, 256, 0, stream>>>(text_w, bio_w, twFL, bwFL);
    k_prep_A <<<256, 256, 0, stream>>>(out_w, in_proj_w, in_proj_b, out_b, A, cvec);
    k_prep_PQ<<<256, 256, 0, stream>>>(cls1_w, cls1_b, A, cvec,
                                       ln_text_g, ln_text_b, ln_bio_g, ln_bio_b,
                                       pqFL, dvec);

    int nrows = in_sizes[0] / 32;     // 65536
    k_main<<<nrows / 32, 256, 0, stream>>>(bio, text, bio_b, text_b,
                                           cls_ln_g, cls_ln_b, cls2_w, cls2_b,
                                           twFL, bwFL, pqFL, dvec, out);
}

// Round 3
// 397.284 us; speedup vs baseline: 2.4768x; 1.0253x over previous
//
#include <hip/hip_runtime.h>

typedef __attribute__((ext_vector_type(4))) float f4;
typedef __attribute__((ext_vector_type(8))) short s8;   // 8 bf16 (4 VGPRs) MFMA frag

#define EPS 1e-5f

__device__ __forceinline__ unsigned short f2bf(float f) {
    union { float f; unsigned u; } v; v.f = f;
    unsigned u = v.u;
    return (unsigned short)((u + 0x7fffu + ((u >> 16) & 1u)) >> 16);   // RNE
}
__device__ __forceinline__ unsigned pack2(float a, float b) {
    return (unsigned)f2bf(a) | ((unsigned)f2bf(b) << 16);
}
__device__ __forceinline__ s8 pack8(f4 a, f4 b) {
    union { s8 v; unsigned u[4]; } r;
    r.u[0] = pack2(a[0], a[1]); r.u[1] = pack2(a[2], a[3]);
    r.u[2] = pack2(b[0], b[1]); r.u[3] = pack2(b[2], b[3]);
    return r.v;
}

// =================== prep1 (merged): weight frag-linear bf16 + A/cvec ===================
// FL layout: FL[((ksg*16 + ct)*64 + lane)*8 + j] = W[ct*16 + (lane&15)][ksg*32 + (lane>>4)*8 + j]
__global__ __launch_bounds__(256) void k_prep1(const float* __restrict__ text_w,
                                               const float* __restrict__ bio_w,
                                               const float* __restrict__ out_w,
                                               const float* __restrict__ in_proj_w,
                                               const float* __restrict__ in_proj_b,
                                               const float* __restrict__ out_b,
                                               unsigned short* __restrict__ twFL,
                                               unsigned short* __restrict__ bwFL,
                                               float* __restrict__ A,
                                               float* __restrict__ cvec) {
    int b = blockIdx.x, t = threadIdx.x;
    if (b < 96) {                       // text_w [256][768] -> 24 ksteps x 16 ct
        int idx = b * 256 + t;
        int ksg = idx >> 10;
        int rem = idx & 1023;
        int ct = rem >> 6, lane = rem & 63;
        int n  = ct * 16 + (lane & 15);
        int k0 = ksg * 32 + ((lane >> 4) << 3);
        const float* src = &text_w[n * 768 + k0];
        f4 a = *(const f4*)src, c = *(const f4*)(src + 4);
        unsigned* dst = (unsigned*)&twFL[idx * 8];
        dst[0] = pack2(a[0], a[1]); dst[1] = pack2(a[2], a[3]);
        dst[2] = pack2(c[0], c[1]); dst[3] = pack2(c[2], c[3]);
    } else if (b < 100) {               // bio_w [256][32] -> 1 kstep x 16 ct
        int idx = (b - 96) * 256 + t;
        int ct = idx >> 6, lane = idx & 63;
        int n  = ct * 16 + (lane & 15);
        int k0 = (lane >> 4) << 3;
        const float* src = &bio_w[n * 32 + k0];
        f4 a = *(const f4*)src, c = *(const f4*)(src + 4);
        unsigned* dst = (unsigned*)&bwFL[idx * 8];
        dst[0] = pack2(a[0], a[1]); dst[1] = pack2(a[2], a[3]);
        dst[2] = pack2(c[0], c[1]); dst[3] = pack2(c[2], c[3]);
    } else {                            // A = out_w @ Wv, cvec = out_w @ bv + out_b
        __shared__ float srow[256];
        __shared__ float red[256];
        int i = b - 100, j = t;
        srow[j] = out_w[i * 256 + j];
        __syncthreads();
        float acc = 0.f;
#pragma unroll 16
        for (int k = 0; k < 256; k++)
            acc = fmaf(srow[k], in_proj_w[(512 + k) * 256 + j], acc);
        A[i * 256 + j] = acc;
        red[j] = srow[j] * in_proj_b[512 + j];
        __syncthreads();
        for (int s = 128; s > 0; s >>= 1) {
            if (j < s) red[j] += red[j + s];
            __syncthreads();
        }
        if (j == 0) cvec[i] = red[0] + out_b[i];
    }
}

// =================== prep2: PQ weights (frag-linear bf16, LN-gain folded) + dvec ===================
__global__ __launch_bounds__(256) void k_prep_PQ(const float* __restrict__ cls1_w,
                                                 const float* __restrict__ cls1_b,
                                                 const float* __restrict__ A,
                                                 const float* __restrict__ cvec,
                                                 const float* __restrict__ ln_text_g,
                                                 const float* __restrict__ ln_text_b,
                                                 const float* __restrict__ ln_bio_g,
                                                 const float* __restrict__ ln_bio_b,
                                                 unsigned short* __restrict__ pqFL,
                                                 float* __restrict__ dvec) {
    __shared__ float w1[256], w2[256], red[256];
    int i = blockIdx.x, j = threadIdx.x;
    w1[j] = cls1_w[i * 512 + j];
    w2[j] = cls1_w[i * 512 + 256 + j];
    __syncthreads();
    float rp = 0.f, rq = 0.f;
#pragma unroll 8
    for (int k = 0; k < 256; k++) {
        float a = A[k * 256 + j];
        rp = fmaf(w1[k], a, rp);
        rq = fmaf(w2[k], a, rq);
    }
    int ct   = i >> 4;
    int lane = (i & 15) | (((j >> 3) & 3) << 4);
    int jj   = j & 7;
    int ks1  = j >> 5;
    pqFL[(((ks1     ) * 16 + ct) * 64 + lane) * 8 + jj] = f2bf(rp * ln_text_g[j]);
    pqFL[(((ks1 + 8 ) * 16 + ct) * 64 + lane) * 8 + jj] = f2bf(rq * ln_bio_g[j]);
    red[j] = rp * ln_text_b[j] + rq * ln_bio_b[j] + (w1[j] + w2[j]) * cvec[j];
    __syncthreads();
    for (int s = 128; s > 0; s >>= 1) {
        if (j < s) red[j] += red[j + s];
        __syncthreads();
    }
    if (j == 0) dvec[i] = red[0] + cls1_b[i];
}

// =================== main fused MFMA kernel ===================
// 64 rows/block, 512 threads = 8 waves: wave = (cs = w&3 col-slice of 64, rh = w>>2 row-half of 32).
// Each wave: 2 row-tiles x 4 col-tiles of 16x16x32_bf16.
// s_x (text chunk, bf16, BK=192) OVERLAYS s_n's n_t half (cols 0..255) — n_t written only
// after all s_x consumption. Text staged via register double-buffer (prefetch chunk c+1
// during chunk c's MFMA).
__global__ __launch_bounds__(512, 4) void k_main(
    const float* __restrict__ bio, const float* __restrict__ text,
    const float* __restrict__ bio_b, const float* __restrict__ text_b,
    const float* __restrict__ cls_ln_g, const float* __restrict__ cls_ln_b,
    const float* __restrict__ cls2_w, const float* __restrict__ cls2_b,
    const unsigned short* __restrict__ twFL, const unsigned short* __restrict__ bwFL,
    const unsigned short* __restrict__ pqFL, const float* __restrict__ dvec,
    float* __restrict__ out)
{
    // row stride 520 u16 = 1040 B = 65*16: 16B-aligned rows, stride ≡ 4 banks → 2-way max on frag reads
    __shared__ __align__(16) unsigned short s_n[64][520];  // 66.6 KB; [row][k] n_t 0..255 | n_b 256..511
    __shared__ float s_red[4][64][2];                      // 2 KB per-colslice row partials

    const int tid  = threadIdx.x;
    const int wv   = tid >> 6;
    const int cs   = wv & 3;          // col slice: cols [cs*64, cs*64+64)
    const int rh   = wv >> 2;         // row half: rows [rh*32, rh*32+32)
    const int lane = tid & 63;
    const int q    = lane >> 4;
    const int lr   = lane & 15;
    const int R0   = blockIdx.x * 64;

    f4 acc[2][4];
    float s1[2][4], s2[2][4], m_[2][4], iv_[2][4];

    // ---- bio A-frag + B-frag loads (issued first) ----
    f4 bioA[2], bioB[2];
#pragma unroll
    for (int rt = 0; rt < 2; rt++) {
        const float* p = &bio[(size_t)(R0 + rh * 32 + rt * 16 + lr) * 32 + q * 8];
        bioA[rt] = *(const f4*)p;
        bioB[rt] = *(const f4*)(p + 4);
    }
    s8 bfrb[4];
#pragma unroll
    for (int c = 0; c < 4; c++)
        bfrb[c] = *(const s8*)&bwFL[((cs * 4 + c) * 64 + lane) * 8];

    // ---- text chunk-0 prefetch (issued after bio loads; independent vmcnt tracking) ----
    int toff[6], soff[6];
    f4 tpre[6];
#pragma unroll
    for (int i = 0; i < 6; i++) {
        int idx = tid + i * 512;          // 3072 f4-slots: 64 rows x 48
        int row = idx / 48;
        int c4  = idx - row * 48;
        toff[i] = (R0 + row) * 768 + c4 * 4;
        soff[i] = row * 520 + c4 * 4;
        tpre[i] = *(const f4*)&text[(size_t)toff[i]];
    }

    // ---------------- stage A: x_b = bio @ bio_w.T + bio_b ; n_b ----------------
#pragma unroll
    for (int rt = 0; rt < 2; rt++)
#pragma unroll
        for (int c = 0; c < 4; c++) acc[rt][c] = (f4){0.f, 0.f, 0.f, 0.f};
#pragma unroll
    for (int rt = 0; rt < 2; rt++) {
        s8 af = pack8(bioA[rt], bioB[rt]);
#pragma unroll
        for (int c = 0; c < 4; c++)
            acc[rt][c] = __builtin_amdgcn_mfma_f32_16x16x32_bf16(af, bfrb[c], acc[rt][c], 0, 0, 0);
    }
#pragma unroll
    for (int rt = 0; rt < 2; rt++)
#pragma unroll
        for (int r = 0; r < 4; r++) { s1[rt][r] = 0.f; s2[rt][r] = 0.f; }
#pragma unroll
    for (int rt = 0; rt < 2; rt++)
#pragma unroll
        for (int c = 0; c < 4; c++) {
            float bb = bio_b[cs * 64 + c * 16 + lr];
#pragma unroll
            for (int r = 0; r < 4; r++) {
                float x = acc[rt][c][r] + bb;
                acc[rt][c][r] = x;
                s1[rt][r] += x; s2[rt][r] += x * x;
            }
        }
#pragma unroll
    for (int off = 1; off < 16; off <<= 1)
#pragma unroll
        for (int rt = 0; rt < 2; rt++)
#pragma unroll
            for (int r = 0; r < 4; r++) {
                s1[rt][r] += __shfl_xor(s1[rt][r], off, 64);
                s2[rt][r] += __shfl_xor(s2[rt][r], off, 64);
            }
    if (lr == 0)
#pragma unroll
        for (int rt = 0; rt < 2; rt++)
#pragma unroll
            for (int r = 0; r < 4; r++) {
                int row = rh * 32 + rt * 16 + q * 4 + r;
                s_red[cs][row][0] = s1[rt][r];
                s_red[cs][row][1] = s2[rt][r];
            }
    __syncthreads();
#pragma unroll
    for (int rt = 0; rt < 2; rt++)
#pragma unroll
        for (int r = 0; r < 4; r++) {
            int row = rh * 32 + rt * 16 + q * 4 + r;
            float t1 = s_red[0][row][0] + s_red[1][row][0] + s_red[2][row][0] + s_red[3][row][0];
            float t2 = s_red[0][row][1] + s_red[1][row][1] + s_red[2][row][1] + s_red[3][row][1];
            float mm = t1 * (1.f / 256.f);
            float vv = t2 * (1.f / 256.f) - mm * mm;
            m_[rt][r]  = mm;
            iv_[rt][r] = rsqrtf(vv + EPS);
        }
#pragma unroll
    for (int rt = 0; rt < 2; rt++)
#pragma unroll
        for (int c = 0; c < 4; c++) {
            int col = cs * 64 + c * 16 + lr;
#pragma unroll
            for (int r = 0; r < 4; r++)
                s_n[rh * 32 + rt * 16 + q * 4 + r][256 + col] =
                    f2bf((acc[rt][c][r] - m_[rt][r]) * iv_[rt][r]);
        }

    // ---------------- stage B: x_t = text @ text_w.T + text_b (K=768, 4 chunks of 192) ----------------
#pragma unroll
    for (int rt = 0; rt < 2; rt++)
#pragma unroll
        for (int c = 0; c < 4; c++) acc[rt][c] = (f4){0.f, 0.f, 0.f, 0.f};

    for (int ch = 0; ch < 4; ch++) {
        if (ch) __syncthreads();          // previous chunk's s_x reads complete
        // pack prefetched regs -> s_x (overlay: s_n[row][0..191])
#pragma unroll
        for (int i = 0; i < 6; i++) {
            uint2 p; p.x = pack2(tpre[i][0], tpre[i][1]); p.y = pack2(tpre[i][2], tpre[i][3]);
            *(uint2*)&((unsigned short*)s_n)[soff[i]] = p;
        }
        // prefetch next chunk (overlaps with this chunk's MFMA)
        if (ch < 3)
#pragma unroll
            for (int i = 0; i < 6; i++)
                tpre[i] = *(const f4*)&text[(size_t)(toff[i] + (ch + 1) * 192)];
        __syncthreads();                  // s_x ready
        int ksg0 = ch * 6;
#pragma unroll
        for (int ks = 0; ks < 6; ks++) {
            s8 bfr[4];
#pragma unroll
            for (int c = 0; c < 4; c++)
                bfr[c] = *(const s8*)&twFL[(((ksg0 + ks) * 16 + cs * 4 + c) * 64 + lane) * 8];
#pragma unroll
            for (int rt = 0; rt < 2; rt++) {
                s8 af = *(const s8*)&s_n[rh * 32 + rt * 16 + lr][ks * 32 + q * 8];
#pragma unroll
                for (int c = 0; c < 4; c++)
                    acc[rt][c] = __builtin_amdgcn_mfma_f32_16x16x32_bf16(af, bfr[c], acc[rt][c], 0, 0, 0);
            }
        }
    }
    // bias + LN stats for text
#pragma unroll
    for (int rt = 0; rt < 2; rt++)
#pragma unroll
        for (int r = 0; r < 4; r++) { s1[rt][r] = 0.f; s2[rt][r] = 0.f; }
#pragma unroll
    for (int rt = 0; rt < 2; rt++)
#pragma unroll
        for (int c = 0; c < 4; c++) {
            float bb = text_b[cs * 64 + c * 16 + lr];
#pragma unroll
            for (int r = 0; r < 4; r++) {
                float x = acc[rt][c][r] + bb;
                acc[rt][c][r] = x;
                s1[rt][r] += x; s2[rt][r] += x * x;
            }
        }
#pragma unroll
    for (int off = 1; off < 16; off <<= 1)
#pragma unroll
        for (int rt = 0; rt < 2; rt++)
#pragma unroll
            for (int r = 0; r < 4; r++) {
                s1[rt][r] += __shfl_xor(s1[rt][r], off, 64);
                s2[rt][r] += __shfl_xor(s2[rt][r], off, 64);
            }
    __syncthreads();   // ALL waves done reading s_x (last chunk) + s_red reads from stage A long done
    if (lr == 0)
#pragma unroll
        for (int rt = 0; rt < 2; rt++)
#pragma unroll
            for (int r = 0; r < 4; r++) {
                int row = rh * 32 + rt * 16 + q * 4 + r;
                s_red[cs][row][0] = s1[rt][r];
                s_red[cs][row][1] = s2[rt][r];
            }
    __syncthreads();
#pragma unroll
    for (int rt = 0; rt < 2; rt++)
#pragma unroll
        for (int r = 0; r < 4; r++) {
            int row = rh * 32 + rt * 16 + q * 4 + r;
            float t1 = s_red[0][row][0] + s_red[1][row][0] + s_red[2][row][0] + s_red[3][row][0];
            float t2 = s_red[0][row][1] + s_red[1][row][1] + s_red[2][row][1] + s_red[3][row][1];
            float mm = t1 * (1.f / 256.f);
            float vv = t2 * (1.f / 256.f) - mm * mm;
            m_[rt][r]  = mm;
            iv_[rt][r] = rsqrtf(vv + EPS);
        }
    // write n_t into cols 0..255 (overwrites s_x region — all consumption barrier'd above)
#pragma unroll
    for (int rt = 0; rt < 2; rt++)
#pragma unroll
        for (int c = 0; c < 4; c++) {
            int col = cs * 64 + c * 16 + lr;
#pragma unroll
            for (int r = 0; r < 4; r++)
                s_n[rh * 32 + rt * 16 + q * 4 + r][col] =
                    f2bf((acc[rt][c][r] - m_[rt][r]) * iv_[rt][r]);
        }
    __syncthreads();   // full s_n = [n_t | n_b] visible to all waves

    // ---------------- stage D: z = Wpq @ [n_t ; n_b] + dvec (K=512) ----------------
#pragma unroll
    for (int rt = 0; rt < 2; rt++)
#pragma unroll
        for (int c = 0; c < 4; c++) {
            float dv = dvec[cs * 64 + c * 16 + lr];
            acc[rt][c] = (f4){dv, dv, dv, dv};
        }
#pragma unroll 4
    for (int ks = 0; ks < 16; ks++) {
        s8 bfr[4];
#pragma unroll
        for (int c = 0; c < 4; c++)
            bfr[c] = *(const s8*)&pqFL[((ks * 16 + cs * 4 + c) * 64 + lane) * 8];
#pragma unroll
        for (int rt = 0; rt < 2; rt++) {
            s8 af = *(const s8*)&s_n[rh * 32 + rt * 16 + lr][ks * 32 + q * 8];
#pragma unroll
            for (int c = 0; c < 4; c++)
                acc[rt][c] = __builtin_amdgcn_mfma_f32_16x16x32_bf16(af, bfr[c], acc[rt][c], 0, 0, 0);
        }
    }

    // ---------------- epilogue: LN(z), relu, cls2 ----------------
#pragma unroll
    for (int rt = 0; rt < 2; rt++)
#pragma unroll
        for (int r = 0; r < 4; r++) { s1[rt][r] = 0.f; s2[rt][r] = 0.f; }
#pragma unroll
    for (int rt = 0; rt < 2; rt++)
#pragma unroll
        for (int c = 0; c < 4; c++)
#pragma unroll
            for (int r = 0; r < 4; r++) {
                float x = acc[rt][c][r];
                s1[rt][r] += x; s2[rt][r] += x * x;
            }
#pragma unroll
    for (int off = 1; off < 16; off <<= 1)
#pragma unroll
        for (int rt = 0; rt < 2; rt++)
#pragma unroll
            for (int r = 0; r < 4; r++) {
                s1[rt][r] += __shfl_xor(s1[rt][r], off, 64);
                s2[rt][r] += __shfl_xor(s2[rt][r], off, 64);
            }
    __syncthreads();   // prior s_red reads done
    if (lr == 0)
#pragma unroll
        for (int rt = 0; rt < 2; rt++)
#pragma unroll
            for (int r = 0; r < 4; r++) {
                int row = rh * 32 + rt * 16 + q * 4 + r;
                s_red[cs][row][0] = s1[rt][r];
                s_red[cs][row][1] = s2[rt][r];
            }
    __syncthreads();
#pragma unroll
    for (int rt = 0; rt < 2; rt++)
#pragma unroll
        for (int r = 0; r < 4; r++) {
            int row = rh * 32 + rt * 16 + q * 4 + r;
            float t1 = s_red[0][row][0] + s_red[1][row][0] + s_red[2][row][0] + s_red[3][row][0];
            float t2 = s_red[0][row][1] + s_red[1][row][1] + s_red[2][row][1] + s_red[3][row][1];
            float mm = t1 * (1.f / 256.f);
            float vv = t2 * (1.f / 256.f) - mm * mm;
            m_[rt][r]  = mm;
            iv_[rt][r] = rsqrtf(vv + EPS);
        }
    float po0[2][4], po1[2][4];
#pragma unroll
    for (int rt = 0; rt < 2; rt++)
#pragma unroll
        for (int r = 0; r < 4; r++) { po0[rt][r] = 0.f; po1[rt][r] = 0.f; }
#pragma unroll
    for (int rt = 0; rt < 2; rt++)
#pragma unroll
        for (int c = 0; c < 4; c++) {
            int col = cs * 64 + c * 16 + lr;
            float gg = cls_ln_g[col], bb = cls_ln_b[col];
            float c0 = cls2_w[col],   c1 = cls2_w[256 + col];
#pragma unroll
            for (int r = 0; r < 4; r++) {
                float h = fmaxf((acc[rt][c][r] - m_[rt][r]) * iv_[rt][r] * gg + bb, 0.f);
                po0[rt][r] = fmaf(h, c0, po0[rt][r]);
                po1[rt][r] = fmaf(h, c1, po1[rt][r]);
            }
        }
#pragma unroll
    for (int off = 1; off < 16; off <<= 1)
#pragma unroll
        for (int rt = 0; rt < 2; rt++)
#pragma unroll
            for (int r = 0; r < 4; r++) {
                po0[rt][r] += __shfl_xor(po0[rt][r], off, 64);
                po1[rt][r] += __shfl_xor(po1[rt][r], off, 64);
            }
    __syncthreads();   // stats reads done; reuse s_red for po
    if (lr == 0)
#pragma unroll
        for (int rt = 0; rt < 2; rt++)
#pragma unroll
            for (int r = 0; r < 4; r++) {
                int row = rh * 32 + rt * 16 + q * 4 + r;
                s_red[cs][row][0] = po0[rt][r];
                s_red[cs][row][1] = po1[rt][r];
            }
    __syncthreads();
    if (tid < 128) {
        int row = tid >> 1, comp = tid & 1;
        float v = s_red[0][row][comp] + s_red[1][row][comp] +
                  s_red[2][row][comp] + s_red[3][row][comp];
        out[(size_t)(R0 + row) * 2 + comp] = v + cls2_b[comp];
    }
}

// ======================= launch =======================
extern "C" void kernel_launch(void* const* d_in, const int* in_sizes, int n_in,
                              void* d_out, int out_size, void* d_ws, size_t ws_size,
                              hipStream_t stream) {
    const float* bio       = (const float*)d_in[0];
    const float* text      = (const float*)d_in[1];
    const float* bio_w     = (const float*)d_in[2];
    const float* bio_b     = (const float*)d_in[3];
    const float* text_w    = (const float*)d_in[4];
    const float* text_b    = (const float*)d_in[5];
    const float* ln_bio_g  = (const float*)d_in[6];
    const float* ln_bio_b  = (const float*)d_in[7];
    const float* ln_text_g = (const float*)d_in[8];
    const float* ln_text_b = (const float*)d_in[9];
    const float* in_proj_w = (const float*)d_in[10];
    const float* in_proj_b = (const float*)d_in[11];
    const float* out_w     = (const float*)d_in[12];
    const float* out_b     = (const float*)d_in[13];
    const float* cls1_w    = (const float*)d_in[14];
    const float* cls1_b    = (const float*)d_in[15];
    const float* cls_ln_g  = (const float*)d_in[16];
    const float* cls_ln_b  = (const float*)d_in[17];
    const float* cls2_w    = (const float*)d_in[18];
    const float* cls2_b    = (const float*)d_in[19];
    float* out = (float*)d_out;

    float* ws   = (float*)d_ws;
    float* A    = ws;                 // 65536 fp32
    float* cvec = ws + 65536;         // 256
    float* dvec = ws + 65792;         // 256
    unsigned short* us   = (unsigned short*)(ws + 66048);
    unsigned short* twFL = us;            // 196608 bf16
    unsigned short* bwFL = us + 196608;   // 8192
    unsigned short* pqFL = us + 204800;   // 131072

    k_prep1  <<<356, 256, 0, stream>>>(text_w, bio_w, out_w, in_proj_w, in_proj_b, out_b,
                                       twFL, bwFL, A, cvec);
    k_prep_PQ<<<256, 256, 0, stream>>>(cls1_w, cls1_b, A, cvec,
                                       ln_text_g, ln_text_b, ln_bio_g, ln_bio_b,
                                       pqFL, dvec);

    int nrows = in_sizes[0] / 32;     // 65536
    k_main<<<nrows / 64, 512, 0, stream>>>(bio, text, bio_b, text_b,
                                           cls_ln_g, cls_ln_b, cls2_w, cls2_b,
                                           twFL, bwFL, pqFL, dvec, out);
}